// Round 1
// baseline (879.093 us; speedup 1.0000x reference)
//
#include <hip/hip_runtime.h>
#include <hip/hip_bf16.h>
#include <math.h>
#include <stdint.h>

#define H     256
#define K2    512
#define SDEC  2048
#define LCSH  14
#define BM    64
#define BK    64
#define NTHR  256

typedef __attribute__((ext_vector_type(8))) short  short8;
typedef __attribute__((ext_vector_type(4))) float  f32x4;

__device__ __forceinline__ unsigned short f2bf(float f) {
  union { float f; unsigned int u; } c; c.f = f;
  unsigned int u = c.u;
  unsigned int r = u + 0x7fffu + ((u >> 16) & 1u);   // RNE
  return (unsigned short)(r >> 16);
}

// Blocks 0..31: fused weight tiles (wft = W1*W2_bot + W2_top, transposed, bf16).
// Block 32: fused bias (biasf = b2 + b1*W2_bot) with 16 loads in flight
// (the old single-block rolled loop was a serial L2-latency chain).
__global__ __launch_bounds__(256) void fuse_weights(
    const float* __restrict__ W1, const float* __restrict__ W2,
    const float* __restrict__ b1, const float* __restrict__ b2,
    unsigned short* __restrict__ wft, float* __restrict__ biasf) {
  if (blockIdx.x == 32) {
    const int n = threadIdx.x;
    float a0 = b2[n], a1 = 0.f, a2 = 0.f, a3 = 0.f;
#pragma unroll 4
    for (int j = 0; j < H; j += 4) {
      a0 += b1[j + 0] * W2[(size_t)(H + j + 0) * H + n];
      a1 += b1[j + 1] * W2[(size_t)(H + j + 1) * H + n];
      a2 += b1[j + 2] * W2[(size_t)(H + j + 2) * H + n];
      a3 += b1[j + 3] * W2[(size_t)(H + j + 3) * H + n];
    }
    biasf[n] = (a0 + a1) + (a2 + a3);
    return;
  }

  __shared__ float As[64][65];
  __shared__ float Bs[64][65];
  const int t  = threadIdx.x;
  const int k0 = (blockIdx.x >> 2) * 64;
  const int n0 = (blockIdx.x & 3) * 64;
  const int lr = t >> 2;
  const int ls = t & 3;
  const int tk = t >> 4;
  const int tn = t & 15;

  float acc[4][4];
#pragma unroll
  for (int i = 0; i < 4; ++i)
#pragma unroll
    for (int c = 0; c < 4; ++c) acc[i][c] = 0.0f;

  for (int jt = 0; jt < 4; ++jt) {
    const int j0 = jt * 64;
    __syncthreads();
    const float* a_src = W1 + (size_t)(k0 + lr) * H + j0 + ls * 16;
    const float* b_src = W2 + (size_t)(H + j0 + lr) * H + n0 + ls * 16;
#pragma unroll
    for (int i = 0; i < 16; ++i) {
      As[lr][ls * 16 + i] = a_src[i];
      Bs[lr][ls * 16 + i] = b_src[i];
    }
    __syncthreads();
#pragma unroll 8
    for (int j = 0; j < 64; ++j) {
      float a[4], b[4];
#pragma unroll
      for (int i = 0; i < 4; ++i) a[i] = As[tk * 4 + i][j];
#pragma unroll
      for (int c = 0; c < 4; ++c) b[c] = Bs[j][tn * 4 + c];
#pragma unroll
      for (int i = 0; i < 4; ++i)
#pragma unroll
        for (int c = 0; c < 4; ++c) acc[i][c] += a[i] * b[c];
    }
  }

#pragma unroll
  for (int i = 0; i < 4; ++i) {
    const int k = k0 + tk * 4 + i;
#pragma unroll
    for (int c = 0; c < 4; ++c) {
      const int n = n0 + tn * 4 + c;
      float v = acc[i][c];
      if (k < H) v += W2[(size_t)k * H + n];
      wft[(size_t)n * K2 + k] = f2bf(v);
    }
  }
}

__global__ __launch_bounds__(NTHR, 6) void syl_main(
    const float* __restrict__ cemb, const int* __restrict__ tal,
    const float* __restrict__ dec, const unsigned short* __restrict__ wft,
    const float* __restrict__ biasf, const float* __restrict__ gamma,
    const float* __restrict__ beta, float* __restrict__ out) {

  // A double-buffer: 2 x 2 x 4 x 64 chunks x 16 B = 16384 B; epilogue reuses
  // as float [16][260] = 16640 B.
  __shared__ __align__(16) char smem[16640];
  unsigned short* AshC = (unsigned short*)smem;
  float* Ef = (float*)smem;

  __shared__ int   idxs[BM];
  __shared__ float msks[BM];
  __shared__ float stats[4][BM][2];

  const int t    = threadIdx.x;
  const int wave = t >> 6;
  const int lane = t & 63;
  const int quad = lane >> 4;
  const int l15  = lane & 15;

  // XCD-chunked swizzle: 2048 blocks = 8 batches x 256; HW round-robins
  // blockIdx%8 across XCDs, so this gives each XCD exactly one batch ->
  // its 2 MB dec slice stays resident in that XCD's L2 for the gather.
  const int nwg  = gridDim.x;
  const int bid  = ((nwg & 7) == 0)
                     ? (int)((blockIdx.x & 7) * (nwg >> 3) + (blockIdx.x >> 3))
                     : (int)blockIdx.x;
  const int row0 = bid * BM;
  const int bidx = row0 >> LCSH;
  const float* decb = dec + (size_t)bidx * SDEC * H;

  if (t < BM) {
    int ix = tal[row0 + t];
    idxs[t] = ix < 0 ? 0 : (ix >= SDEC ? SDEC - 1 : ix);
    msks[t] = ix < 0 ? 0.0f : 1.0f;
  }

  f32x4 acc[4][4];
#pragma unroll
  for (int m = 0; m < 4; ++m)
#pragma unroll
    for (int n = 0; n < 4; ++n) acc[m][n] = (f32x4){0.f, 0.f, 0.f, 0.f};

  const int srow = t >> 2;
  const int sseg = t & 3;
  const int ksS  = sseg >> 1;
  const int qS   = (sseg & 1) * 2;
  const int mS   = srow >> 4;
  const int l15S = srow & 15;
  const int wchunk0 = (ksS * 4 + mS) * 64 + qS * 16 + l15S;

  // prologue: stage ki=0 (char half only)
  {
    const float* src = cemb + (size_t)(row0 + srow) * H + sseg * 16;
    float4 f[4];
#pragma unroll
    for (int q = 0; q < 4; ++q) f[q] = *(const float4*)(src + q * 4);
    unsigned short hb[16];
#pragma unroll
    for (int q = 0; q < 4; ++q) {
      hb[q * 4 + 0] = f2bf(f[q].x); hb[q * 4 + 1] = f2bf(f[q].y);
      hb[q * 4 + 2] = f2bf(f[q].z); hb[q * 4 + 3] = f2bf(f[q].w);
    }
    *(short8*)(AshC + (size_t)wchunk0 * 8)        = *(short8*)&hb[0];
    *(short8*)(AshC + (size_t)(wchunk0 + 16) * 8) = *(short8*)&hb[8];
  }
  __syncthreads();

  int buf = 0;
  for (int ki = 0; ki < 8; ++ki) {
    const int k0 = ki * BK;

    // B fragments from global first (their waits leave A-prefetch in flight)
    short8 bf[2][4];
#pragma unroll
    for (int ks = 0; ks < 2; ++ks)
#pragma unroll
      for (int n = 0; n < 4; ++n) {
        const unsigned short* bp =
            wft + (size_t)(wave * 64 + n * 16 + l15) * K2 + k0 + ks * 32 + quad * 8;
        bf[ks][n] = *(const short8*)bp;
      }

    // prefetch next A tile (fp32) into registers
    float4 f[4];
    float scale = 1.0f;
    if (ki < 7) {
      const int k0n = k0 + BK;
      const float* src;
      if (k0n < H) {
        src = cemb + (size_t)(row0 + srow) * H + k0n + sseg * 16;
      } else {
        src = decb + (size_t)idxs[srow] * H + (k0n - H) + sseg * 16;
        scale = msks[srow];
      }
#pragma unroll
      for (int q = 0; q < 4; ++q) f[q] = *(const float4*)(src + q * 4);
    }

    // MFMA on current buffer (linear-in-lane ds_read_b128)
#pragma unroll
    for (int ks = 0; ks < 2; ++ks) {
      short8 af[4];
#pragma unroll
      for (int m = 0; m < 4; ++m)
        af[m] = *(const short8*)(AshC +
                 (size_t)(((buf * 2 + ks) * 4 + m) * 64 + lane) * 8);
#pragma unroll
      for (int n = 0; n < 4; ++n)
#pragma unroll
        for (int m = 0; m < 4; ++m)
          acc[m][n] = __builtin_amdgcn_mfma_f32_16x16x32_bf16(
              af[m], bf[ks][n], acc[m][n], 0, 0, 0);
    }

    // convert + write next buffer, single barrier
    if (ki < 7) {
      unsigned short hb[16];
#pragma unroll
      for (int q = 0; q < 4; ++q) {
        hb[q * 4 + 0] = f2bf(f[q].x * scale); hb[q * 4 + 1] = f2bf(f[q].y * scale);
        hb[q * 4 + 2] = f2bf(f[q].z * scale); hb[q * 4 + 3] = f2bf(f[q].w * scale);
      }
      const int nb = buf ^ 1;
      *(short8*)(AshC + (size_t)(nb * 512 + wchunk0) * 8)      = *(short8*)&hb[0];
      *(short8*)(AshC + (size_t)(nb * 512 + wchunk0 + 16) * 8) = *(short8*)&hb[8];
      __syncthreads();
      buf = nb;
    }
  }

  // epilogue: bias + LN stats
  float bvals[4], gvals[4], betv[4];
#pragma unroll
  for (int n = 0; n < 4; ++n) {
    const int col = wave * 64 + n * 16 + l15;
    bvals[n] = biasf[col];
    gvals[n] = gamma[col];
    betv[n]  = beta[col];
  }
#pragma unroll
  for (int m = 0; m < 4; ++m)
#pragma unroll
    for (int n = 0; n < 4; ++n)
#pragma unroll
      for (int r = 0; r < 4; ++r) acc[m][n][r] += bvals[n];

#pragma unroll
  for (int m = 0; m < 4; ++m)
#pragma unroll
    for (int r = 0; r < 4; ++r) {
      float a = 0.f, b = 0.f;
#pragma unroll
      for (int n = 0; n < 4; ++n) {
        const float v = acc[m][n][r];
        a += v; b += v * v;
      }
#pragma unroll
      for (int d = 1; d < 16; d <<= 1) {
        a += __shfl_xor(a, d, 64);
        b += __shfl_xor(b, d, 64);
      }
      if (l15 == 0) {
        const int row = m * 16 + quad * 4 + r;
        stats[wave][row][0] = a;
        stats[wave][row][1] = b;
      }
    }
  __syncthreads();   // also guards smem reuse (all MFMA ds_reads complete)

  float mean_[4][4], rstd_[4][4];
#pragma unroll
  for (int m = 0; m < 4; ++m)
#pragma unroll
    for (int r = 0; r < 4; ++r) {
      const int row = m * 16 + quad * 4 + r;
      const float a = stats[0][row][0] + stats[1][row][0] +
                      stats[2][row][0] + stats[3][row][0];
      const float b = stats[0][row][1] + stats[1][row][1] +
                      stats[2][row][1] + stats[3][row][1];
      const float mu  = a * (1.0f / 256.0f);
      const float var = b * (1.0f / 256.0f) - mu * mu;
      mean_[m][r] = mu;
      rstd_[m][r] = rsqrtf(var + 1e-5f);
    }

  // LN + GELU + residual via LDS transpose, float4 I/O
  const int erow = t >> 4;
  const int eseg = t & 15;
#pragma unroll
  for (int m = 0; m < 4; ++m) {
#pragma unroll
    for (int r = 0; r < 4; ++r) {
#pragma unroll
      for (int n = 0; n < 4; ++n) {
        const float x = (acc[m][n][r] - mean_[m][r]) * rstd_[m][r];
        const float y = x * gvals[n] + betv[n];
        const float g = 0.5f * y * (1.0f + erff(y * 0.70710678118654752f));
        Ef[(quad * 4 + r) * 260 + wave * 64 + n * 16 + l15] = g;
      }
    }
    __syncthreads();
    {
      const size_t grow = (size_t)row0 + m * 16 + erow;
      const float* crow = cemb + grow * H + eseg * 16;
      float* orow = out + grow * H + eseg * 16;
#pragma unroll
      for (int j = 0; j < 4; ++j) {
        float4 v = *(const float4*)&Ef[erow * 260 + eseg * 16 + j * 4];
        float4 c = *(const float4*)(crow + j * 4);
        v.x += c.x; v.y += c.y; v.z += c.z; v.w += c.w;
        *(float4*)(orow + j * 4) = v;
      }
    }
    __syncthreads();
  }
}

extern "C" void kernel_launch(void* const* d_in, const int* in_sizes, int n_in,
                              void* d_out, int out_size, void* d_ws, size_t ws_size,
                              hipStream_t stream) {
  const float* cemb  = (const float*)d_in[0];
  const int*   tal   = (const int*)d_in[1];
  const float* dec   = (const float*)d_in[2];
  const float* W1    = (const float*)d_in[3];
  const float* b1    = (const float*)d_in[4];
  const float* W2    = (const float*)d_in[5];
  const float* b2    = (const float*)d_in[6];
  const float* gamma = (const float*)d_in[7];
  const float* beta  = (const float*)d_in[8];
  float* out = (float*)d_out;

  unsigned short* wft = (unsigned short*)d_ws;
  float* biasf = (float*)((char*)d_ws + (size_t)K2 * H * sizeof(unsigned short));

  const int rows = in_sizes[0] / H;   // 131072

  hipLaunchKernelGGL(fuse_weights, dim3(33), dim3(256), 0, stream,
                     W1, W2, b1, b2, wft, biasf);
  hipLaunchKernelGGL(syl_main, dim3(rows / BM), dim3(NTHR), 0, stream,
                     cemb, tal, dec, wft, biasf, gamma, beta, out);
}

// Round 2
// 405.593 us; speedup vs baseline: 2.1674x; 2.1674x over previous
//
#include <hip/hip_runtime.h>
#include <hip/hip_bf16.h>
#include <math.h>
#include <stdint.h>

#define H     256
#define K2    512
#define SDEC  2048
#define LCSH  14
#define BM    64
#define BK    64
#define NTHR  256

typedef __attribute__((ext_vector_type(8))) short  short8;
typedef __attribute__((ext_vector_type(4))) float  f32x4;

__device__ __forceinline__ unsigned short f2bf(float f) {
  union { float f; unsigned int u; } c; c.f = f;
  unsigned int u = c.u;
  unsigned int r = u + 0x7fffu + ((u >> 16) & 1u);   // RNE
  return (unsigned short)(r >> 16);
}

// Blocks 0..31: fused weight tiles (wft = W1*W2_bot + W2_top, transposed, bf16).
// Block 32: fused bias (biasf = b2 + b1*W2_bot) with 16 loads in flight.
__global__ __launch_bounds__(256) void fuse_weights(
    const float* __restrict__ W1, const float* __restrict__ W2,
    const float* __restrict__ b1, const float* __restrict__ b2,
    unsigned short* __restrict__ wft, float* __restrict__ biasf) {
  if (blockIdx.x == 32) {
    const int n = threadIdx.x;
    float a0 = b2[n], a1 = 0.f, a2 = 0.f, a3 = 0.f;
#pragma unroll 4
    for (int j = 0; j < H; j += 4) {
      a0 += b1[j + 0] * W2[(size_t)(H + j + 0) * H + n];
      a1 += b1[j + 1] * W2[(size_t)(H + j + 1) * H + n];
      a2 += b1[j + 2] * W2[(size_t)(H + j + 2) * H + n];
      a3 += b1[j + 3] * W2[(size_t)(H + j + 3) * H + n];
    }
    biasf[n] = (a0 + a1) + (a2 + a3);
    return;
  }

  __shared__ float As[64][65];
  __shared__ float Bs[64][65];
  const int t  = threadIdx.x;
  const int k0 = (blockIdx.x >> 2) * 64;
  const int n0 = (blockIdx.x & 3) * 64;
  const int lr = t >> 2;
  const int ls = t & 3;
  const int tk = t >> 4;
  const int tn = t & 15;

  float acc[4][4];
#pragma unroll
  for (int i = 0; i < 4; ++i)
#pragma unroll
    for (int c = 0; c < 4; ++c) acc[i][c] = 0.0f;

  for (int jt = 0; jt < 4; ++jt) {
    const int j0 = jt * 64;
    __syncthreads();
    const float* a_src = W1 + (size_t)(k0 + lr) * H + j0 + ls * 16;
    const float* b_src = W2 + (size_t)(H + j0 + lr) * H + n0 + ls * 16;
#pragma unroll
    for (int i = 0; i < 16; ++i) {
      As[lr][ls * 16 + i] = a_src[i];
      Bs[lr][ls * 16 + i] = b_src[i];
    }
    __syncthreads();
#pragma unroll 8
    for (int j = 0; j < 64; ++j) {
      float a[4], b[4];
#pragma unroll
      for (int i = 0; i < 4; ++i) a[i] = As[tk * 4 + i][j];
#pragma unroll
      for (int c = 0; c < 4; ++c) b[c] = Bs[j][tn * 4 + c];
#pragma unroll
      for (int i = 0; i < 4; ++i)
#pragma unroll
        for (int c = 0; c < 4; ++c) acc[i][c] += a[i] * b[c];
    }
  }

#pragma unroll
  for (int i = 0; i < 4; ++i) {
    const int k = k0 + tk * 4 + i;
#pragma unroll
    for (int c = 0; c < 4; ++c) {
      const int n = n0 + tn * 4 + c;
      float v = acc[i][c];
      if (k < H) v += W2[(size_t)k * H + n];
      wft[(size_t)n * K2 + k] = f2bf(v);
    }
  }
}

// R1: reverted launch_bounds(256,6) -> (256,3). True reg footprint is
// ~84 VGPR + 64 AGPR (unified file) = ~148; 6 waves/SIMD forced spill storm
// (VGPR 40, WRITE 1.5 GB scratch). 3 blocks/CU is the hardware max here.
// R1: prefetch distance 2 on the A tile — loads issued at ki land at end
// of ki+1, so each HBM load has a full K-iteration to complete.
__global__ __launch_bounds__(NTHR, 3) void syl_main(
    const float* __restrict__ cemb, const int* __restrict__ tal,
    const float* __restrict__ dec, const unsigned short* __restrict__ wft,
    const float* __restrict__ biasf, const float* __restrict__ gamma,
    const float* __restrict__ beta, float* __restrict__ out) {

  // A double-buffer: 2 x 2 x 4 x 64 chunks x 16 B = 16384 B; epilogue reuses
  // as float [16][260] = 16640 B.
  __shared__ __align__(16) char smem[16640];
  unsigned short* AshC = (unsigned short*)smem;
  float* Ef = (float*)smem;

  __shared__ int   idxs[BM];
  __shared__ float msks[BM];
  __shared__ float stats[4][BM][2];

  const int t    = threadIdx.x;
  const int wave = t >> 6;
  const int lane = t & 63;
  const int quad = lane >> 4;
  const int l15  = lane & 15;

  // XCD-chunked swizzle: 2048 blocks = 8 batches x 256; HW round-robins
  // blockIdx%8 across XCDs, so this gives each XCD exactly one batch ->
  // its 2 MB dec slice stays resident in that XCD's L2 for the gather.
  const int nwg  = gridDim.x;
  const int bid  = ((nwg & 7) == 0)
                     ? (int)((blockIdx.x & 7) * (nwg >> 3) + (blockIdx.x >> 3))
                     : (int)blockIdx.x;
  const int row0 = bid * BM;
  const int bidx = row0 >> LCSH;
  const float* decb = dec + (size_t)bidx * SDEC * H;

  if (t < BM) {
    int ix = tal[row0 + t];
    idxs[t] = ix < 0 ? 0 : (ix >= SDEC ? SDEC - 1 : ix);
    msks[t] = ix < 0 ? 0.0f : 1.0f;
  }

  f32x4 acc[4][4];
#pragma unroll
  for (int m = 0; m < 4; ++m)
#pragma unroll
    for (int n = 0; n < 4; ++n) acc[m][n] = (f32x4){0.f, 0.f, 0.f, 0.f};

  const int srow = t >> 2;
  const int sseg = t & 3;
  const int ksS  = sseg >> 1;
  const int qS   = (sseg & 1) * 2;
  const int mS   = srow >> 4;
  const int l15S = srow & 15;
  const int wchunk0 = (ksS * 4 + mS) * 64 + qS * 16 + l15S;

  const float* arow_c = cemb + (size_t)(row0 + srow) * H + sseg * 16;

  // prologue: stage tile 0 (char half) into LDS buf0
  {
    float4 f[4];
#pragma unroll
    for (int q = 0; q < 4; ++q) f[q] = *(const float4*)(arow_c + q * 4);
    unsigned short hb[16];
#pragma unroll
    for (int q = 0; q < 4; ++q) {
      hb[q * 4 + 0] = f2bf(f[q].x); hb[q * 4 + 1] = f2bf(f[q].y);
      hb[q * 4 + 2] = f2bf(f[q].z); hb[q * 4 + 3] = f2bf(f[q].w);
    }
    *(short8*)(AshC + (size_t)wchunk0 * 8)        = *(short8*)&hb[0];
    *(short8*)(AshC + (size_t)(wchunk0 + 16) * 8) = *(short8*)&hb[8];
  }
  __syncthreads();   // buf0 ready; idxs/msks visible

  const int   myidx = idxs[srow];
  const float mymsk = msks[srow];
  const float* arow_d = decb + (size_t)myidx * H + sseg * 16;

  // pipeline registers: pf[(ki+1)&1] holds tile ki+1 at top of iter ki
  float4 pf[2][4];
#pragma unroll
  for (int q = 0; q < 4; ++q) pf[1][q] = *(const float4*)(arow_c + BK + q * 4);

#pragma unroll
  for (int ki = 0; ki < 8; ++ki) {
    const int k0 = ki * BK;
    const int buf = ki & 1;

    // B fragments from global (L2-resident wft)
    short8 bf[2][4];
#pragma unroll
    for (int ks = 0; ks < 2; ++ks)
#pragma unroll
      for (int n = 0; n < 4; ++n) {
        const unsigned short* bp =
            wft + (size_t)(wave * 64 + n * 16 + l15) * K2 + k0 + ks * 32 + quad * 8;
        bf[ks][n] = *(const short8*)bp;
      }

    // issue loads for tile ki+2 (consumed at end of NEXT iteration)
    if (ki < 6) {
      const int kt = k0 + 2 * BK;
      const float* src = (kt < H) ? (arow_c + kt) : (arow_d + (kt - H));
#pragma unroll
      for (int q = 0; q < 4; ++q) pf[ki & 1][q] = *(const float4*)(src + q * 4);
    }

    // MFMA on current buffer (linear-in-lane ds_read_b128)
#pragma unroll
    for (int ks = 0; ks < 2; ++ks) {
      short8 af[4];
#pragma unroll
      for (int m = 0; m < 4; ++m)
        af[m] = *(const short8*)(AshC +
                 (size_t)(((buf * 2 + ks) * 4 + m) * 64 + lane) * 8);
#pragma unroll
      for (int n = 0; n < 4; ++n)
#pragma unroll
        for (int m = 0; m < 4; ++m)
          acc[m][n] = __builtin_amdgcn_mfma_f32_16x16x32_bf16(
              af[m], bf[ks][n], acc[m][n], 0, 0, 0);
    }

    // convert + write tile ki+1 (loaded a full iteration ago), single barrier
    if (ki < 7) {
      const float sc = ((k0 + BK) >= H) ? mymsk : 1.0f;
      const float4* fw = pf[(ki + 1) & 1];
      unsigned short hb[16];
#pragma unroll
      for (int q = 0; q < 4; ++q) {
        hb[q * 4 + 0] = f2bf(fw[q].x * sc); hb[q * 4 + 1] = f2bf(fw[q].y * sc);
        hb[q * 4 + 2] = f2bf(fw[q].z * sc); hb[q * 4 + 3] = f2bf(fw[q].w * sc);
      }
      const int nb = buf ^ 1;
      *(short8*)(AshC + (size_t)(nb * 512 + wchunk0) * 8)      = *(short8*)&hb[0];
      *(short8*)(AshC + (size_t)(nb * 512 + wchunk0 + 16) * 8) = *(short8*)&hb[8];
      __syncthreads();
    }
  }

  // epilogue: bias + LN stats
  float bvals[4], gvals[4], betv[4];
#pragma unroll
  for (int n = 0; n < 4; ++n) {
    const int col = wave * 64 + n * 16 + l15;
    bvals[n] = biasf[col];
    gvals[n] = gamma[col];
    betv[n]  = beta[col];
  }
#pragma unroll
  for (int m = 0; m < 4; ++m)
#pragma unroll
    for (int n = 0; n < 4; ++n)
#pragma unroll
      for (int r = 0; r < 4; ++r) acc[m][n][r] += bvals[n];

#pragma unroll
  for (int m = 0; m < 4; ++m)
#pragma unroll
    for (int r = 0; r < 4; ++r) {
      float a = 0.f, b = 0.f;
#pragma unroll
      for (int n = 0; n < 4; ++n) {
        const float v = acc[m][n][r];
        a += v; b += v * v;
      }
#pragma unroll
      for (int d = 1; d < 16; d <<= 1) {
        a += __shfl_xor(a, d, 64);
        b += __shfl_xor(b, d, 64);
      }
      if (l15 == 0) {
        const int row = m * 16 + quad * 4 + r;
        stats[wave][row][0] = a;
        stats[wave][row][1] = b;
      }
    }
  __syncthreads();   // also guards smem reuse (all MFMA ds_reads complete)

  float mean_[4][4], rstd_[4][4];
#pragma unroll
  for (int m = 0; m < 4; ++m)
#pragma unroll
    for (int r = 0; r < 4; ++r) {
      const int row = m * 16 + quad * 4 + r;
      const float a = stats[0][row][0] + stats[1][row][0] +
                      stats[2][row][0] + stats[3][row][0];
      const float b = stats[0][row][1] + stats[1][row][1] +
                      stats[2][row][1] + stats[3][row][1];
      const float mu  = a * (1.0f / 256.0f);
      const float var = b * (1.0f / 256.0f) - mu * mu;
      mean_[m][r] = mu;
      rstd_[m][r] = rsqrtf(var + 1e-5f);
    }

  // LN + GELU + residual via LDS transpose, float4 I/O
  const int erow = t >> 4;
  const int eseg = t & 15;
#pragma unroll
  for (int m = 0; m < 4; ++m) {
#pragma unroll
    for (int r = 0; r < 4; ++r) {
#pragma unroll
      for (int n = 0; n < 4; ++n) {
        const float x = (acc[m][n][r] - mean_[m][r]) * rstd_[m][r];
        const float y = x * gvals[n] + betv[n];
        const float g = 0.5f * y * (1.0f + erff(y * 0.70710678118654752f));
        Ef[(quad * 4 + r) * 260 + wave * 64 + n * 16 + l15] = g;
      }
    }
    __syncthreads();
    {
      const size_t grow = (size_t)row0 + m * 16 + erow;
      const float* crow = cemb + grow * H + eseg * 16;
      float* orow = out + grow * H + eseg * 16;
#pragma unroll
      for (int j = 0; j < 4; ++j) {
        float4 v = *(const float4*)&Ef[erow * 260 + eseg * 16 + j * 4];
        float4 c = *(const float4*)(crow + j * 4);
        v.x += c.x; v.y += c.y; v.z += c.z; v.w += c.w;
        *(float4*)(orow + j * 4) = v;
      }
    }
    __syncthreads();
  }
}

extern "C" void kernel_launch(void* const* d_in, const int* in_sizes, int n_in,
                              void* d_out, int out_size, void* d_ws, size_t ws_size,
                              hipStream_t stream) {
  const float* cemb  = (const float*)d_in[0];
  const int*   tal   = (const int*)d_in[1];
  const float* dec   = (const float*)d_in[2];
  const float* W1    = (const float*)d_in[3];
  const float* b1    = (const float*)d_in[4];
  const float* W2    = (const float*)d_in[5];
  const float* b2    = (const float*)d_in[6];
  const float* gamma = (const float*)d_in[7];
  const float* beta  = (const float*)d_in[8];
  float* out = (float*)d_out;

  unsigned short* wft = (unsigned short*)d_ws;
  float* biasf = (float*)((char*)d_ws + (size_t)K2 * H * sizeof(unsigned short));

  const int rows = in_sizes[0] / H;   // 131072

  hipLaunchKernelGGL(fuse_weights, dim3(33), dim3(256), 0, stream,
                     W1, W2, b1, b2, wft, biasf);
  hipLaunchKernelGGL(syl_main, dim3(rows / BM), dim3(NTHR), 0, stream,
                     cemb, tal, dec, wft, biasf, gamma, beta, out);
}